// Round 14
// baseline (69.111 us; speedup 1.0000x reference)
//
#include <hip/hip_runtime.h>

// Problem: B=4, N=512, D=256, H=256, M = B*N = 2048
// out[b,i,j] = 0.5*(E + E^T),  E[b,i,j] = sum_h v[h]*tanh(Q[b,i,h]+K[b,j,h])
// tanh(q+k) = 1 - 2/(1+e^{2q}e^{2k}); u=exp2(C2*q), w=exp2(C2*k), C2=2*log2(e)
// P_ij = sum_h v_h/(1+u_ih w_jh);  out_ij = Sv - P_ij - P_ji
// 8-way rcp batching (1 rcp / 8 terms) via common-denominator tree.
// Overflow: u pre-scaled 2^-8 (clamp 4), w clamp 1024; leaf A=fma(u',w,2^-8);
//   M = prod8 <= 4096^8 ~ 8e28 safe; fold 2^-8 into final atomic.
// Round 14: exact round-10 pipeline (best: 57.4us); single knob change:
//   pairwise launch_bounds (512,4) -> (512,6): VGPR cap 128 -> ~85.
//   TREE8 live set ~60-70 -> should fit w/o spill -> 24 waves/CU (was 16).
//   (512,8) pinned VGPR=32 and spilled (r5); (512,4) leaves occupancy on
//   the table. Check: pairwise WRITE_SIZE must stay ~MBs (spill = balloons).

typedef float f4 __attribute__((ext_vector_type(4)));
typedef float f32x4 __attribute__((ext_vector_type(4)));
typedef __bf16 bf16x8 __attribute__((ext_vector_type(8)));

#define C2F 2.8853900817779268f
#define S8  0.00390625f   // 2^-8

__device__ inline unsigned short f2bf(float f) {
    unsigned u = __float_as_uint(f);
    unsigned r = (u + 0x7fffu + ((u >> 16) & 1u)) >> 16;
    return (unsigned short)r;
}
__device__ inline float bf2f(unsigned short h) {
    return __uint_as_float(((unsigned)h) << 16);
}

__device__ inline void split4(const f4 a, unsigned short* hp, unsigned short* lp) {
    unsigned short h[4], l[4];
#pragma unroll
    for (int t = 0; t < 4; ++t) {
        h[t] = f2bf(a[t]);
        l[t] = f2bf(a[t] - bf2f(h[t]));
    }
    uint2 hv, lv;
    hv.x = (unsigned)h[0] | ((unsigned)h[1] << 16);
    hv.y = (unsigned)h[2] | ((unsigned)h[3] << 16);
    lv.x = (unsigned)l[0] | ((unsigned)l[1] << 16);
    lv.y = (unsigned)l[2] | ((unsigned)l[3] << 16);
    *(uint2*)hp = hv;
    *(uint2*)lp = lv;
}

// ---------------------------------------------------------------------------
// gemm_fullk: C[m,n] = act(sum_k A[m,k]*Wsel[n,k] + bias[n]), K=256 resident.
// ACT==2: col<256 -> min(exp2(C2*x-8),4); col>=256 -> min(exp2(C2*x),1024)
// ---------------------------------------------------------------------------
template <int ACT>
__global__ __launch_bounds__(256) void gemm_fullk(
    const float* __restrict__ A, const float* __restrict__ Wa,
    const float* __restrict__ Wb, const float* __restrict__ ba,
    const float* __restrict__ bb2, float* __restrict__ C, int Nn) {
    __shared__ unsigned short sAhi[64][264];
    __shared__ unsigned short sAlo[64][264];
    __shared__ unsigned short sBhi[64][264];
    __shared__ unsigned short sBlo[64][264];

    const int tid = threadIdx.x;
    const int m0 = blockIdx.x << 6;
    const int n0 = blockIdx.y << 6;

    const float* Atile = A + (size_t)m0 * 256;
    const float* Wtile = (n0 < 256) ? (Wa + (size_t)n0 * 256)
                                    : (Wb + (size_t)(n0 - 256) * 256);
    const int col4 = (tid & 63) << 2;
    const int rgrp = tid >> 6;
#pragma unroll
    for (int t = 0; t < 16; ++t) {
        const int row = (t << 2) + rgrp;
        f4 av = *(const f4*)&Atile[(size_t)row * 256 + col4];
        f4 wv = *(const f4*)&Wtile[(size_t)row * 256 + col4];
        split4(av, &sAhi[row][col4], &sAlo[row][col4]);
        split4(wv, &sBhi[row][col4], &sBlo[row][col4]);
    }
    __syncthreads();

    const int lane = tid & 63;
    const int wav = tid >> 6;
    const int wm = wav >> 1, wn = wav & 1;
    const int fr = lane & 15;
    const int fks = (lane >> 4) << 3;

    f32x4 acc[2][2];
#pragma unroll
    for (int i = 0; i < 2; ++i)
#pragma unroll
        for (int j = 0; j < 2; ++j) acc[i][j] = (f32x4){0.f, 0.f, 0.f, 0.f};

#pragma unroll
    for (int kt = 0; kt < 256; kt += 32) {
        bf16x8 ah[2], al[2], bh[2], bl[2];
#pragma unroll
        for (int s = 0; s < 2; ++s) {
            ah[s] = *(const bf16x8*)&sAhi[(wm << 5) + (s << 4) + fr][kt + fks];
            al[s] = *(const bf16x8*)&sAlo[(wm << 5) + (s << 4) + fr][kt + fks];
            bh[s] = *(const bf16x8*)&sBhi[(wn << 5) + (s << 4) + fr][kt + fks];
            bl[s] = *(const bf16x8*)&sBlo[(wn << 5) + (s << 4) + fr][kt + fks];
        }
#pragma unroll
        for (int i = 0; i < 2; ++i)
#pragma unroll
            for (int j = 0; j < 2; ++j) {
                acc[i][j] = __builtin_amdgcn_mfma_f32_16x16x32_bf16(ah[i], bh[j], acc[i][j], 0, 0, 0);
                acc[i][j] = __builtin_amdgcn_mfma_f32_16x16x32_bf16(ah[i], bl[j], acc[i][j], 0, 0, 0);
                acc[i][j] = __builtin_amdgcn_mfma_f32_16x16x32_bf16(al[i], bh[j], acc[i][j], 0, 0, 0);
            }
    }

    const int rbase = (lane >> 4) << 2;
#pragma unroll
    for (int i = 0; i < 2; ++i) {
#pragma unroll
        for (int j = 0; j < 2; ++j) {
            const int gcol = n0 + (wn << 5) + (j << 4) + fr;
            const float bias = (ACT == 2 && gcol >= 256) ? bb2[gcol - 256] : ba[gcol];
#pragma unroll
            for (int q = 0; q < 4; ++q) {
                const int grow = m0 + (wm << 5) + (i << 4) + rbase + q;
                float x = acc[i][j][q] + bias;
                if (ACT == 1)
                    x = 1.0f - 2.0f * __builtin_amdgcn_rcpf(
                                          1.0f + __builtin_amdgcn_exp2f(C2F * x));
                if (ACT == 2) {
                    if (gcol < 256)
                        x = fminf(__builtin_amdgcn_exp2f(C2F * x - 8.0f), 4.0f);
                    else
                        x = fminf(__builtin_amdgcn_exp2f(C2F * x), 1024.0f);
                }
                C[(size_t)grow * Nn + gcol] = x;
            }
        }
    }
}

// ---------------------------------------------------------------------------
// gemm_stage1: fused launch.
//  blocks [0,128): h1 = tanh(X @ W1^T + b1)
//  blocks [128,160): Wc = [Wq;Wk] @ W2 (B not transp.), bc = Asel@b2 + bias
//  blocks [160,224): zero Ep (1M floats)
// ---------------------------------------------------------------------------
__global__ __launch_bounds__(256) void gemm_stage1(
    const float* __restrict__ X, const float* __restrict__ W1,
    const float* __restrict__ b1, const float* __restrict__ Wq,
    const float* __restrict__ Wk, const float* __restrict__ W2,
    const float* __restrict__ b2, const float* __restrict__ bq,
    const float* __restrict__ bk, float* __restrict__ h1,
    float* __restrict__ Wc, float* __restrict__ bc,
    float* __restrict__ Ep) {
    __shared__ unsigned short sAhi[64][264];
    __shared__ unsigned short sAlo[64][264];
    __shared__ unsigned short sBhi[64][264];
    __shared__ unsigned short sBlo[64][264];
    __shared__ float sred[64][4];

    const int tid = threadIdx.x;

    if (blockIdx.x >= 160) {
        const int zb = blockIdx.x - 160;
        f4* dst = (f4*)(Ep + (size_t)zb * 16384) + tid;
        const f4 z = (f4){0.f, 0.f, 0.f, 0.f};
#pragma unroll
        for (int t = 0; t < 16; ++t) dst[t * 256] = z;
        return;
    }

    const bool is_nt = (blockIdx.x >= 128);
    const int blk = is_nt ? (blockIdx.x - 128) : blockIdx.x;
    const int m0 = (blk >> 2) << 6;
    const int n0 = (blk & 3) << 6;

    const int col4 = (tid & 63) << 2;
    const int rgrp = tid >> 6;

    if (!is_nt) {
        const float* Atile = X + (size_t)m0 * 256;
        const float* Wtile = W1 + (size_t)n0 * 256;
#pragma unroll
        for (int t = 0; t < 16; ++t) {
            const int row = (t << 2) + rgrp;
            f4 av = *(const f4*)&Atile[(size_t)row * 256 + col4];
            f4 wv = *(const f4*)&Wtile[(size_t)row * 256 + col4];
            split4(av, &sAhi[row][col4], &sAlo[row][col4]);
            split4(wv, &sBhi[row][col4], &sBlo[row][col4]);
        }
    } else {
        const float* Atile = (m0 < 256) ? (Wq + (size_t)m0 * 256)
                                        : (Wk + (size_t)(m0 - 256) * 256);
#pragma unroll
        for (int t = 0; t < 16; ++t) {
            const int row = (t << 2) + rgrp;
            f4 av = *(const f4*)&Atile[(size_t)row * 256 + col4];
            split4(av, &sAhi[row][col4], &sAlo[row][col4]);
        }
        const int c4 = (tid & 15) << 2;
        const int kg = tid >> 4;
#pragma unroll
        for (int t = 0; t < 16; ++t) {
            const int k = (t << 4) + kg;
            f4 wv = *(const f4*)&W2[(size_t)k * 256 + n0 + c4];
#pragma unroll
            for (int q = 0; q < 4; ++q) {
                unsigned short hi = f2bf(wv[q]);
                sBhi[c4 + q][k] = hi;
                sBlo[c4 + q][k] = f2bf(wv[q] - bf2f(hi));
            }
        }
    }
    __syncthreads();

    const int lane = tid & 63;
    const int wav = tid >> 6;
    const int wm = wav >> 1, wn = wav & 1;
    const int fr = lane & 15;
    const int fks = (lane >> 4) << 3;

    f32x4 acc[2][2];
#pragma unroll
    for (int i = 0; i < 2; ++i)
#pragma unroll
        for (int j = 0; j < 2; ++j) acc[i][j] = (f32x4){0.f, 0.f, 0.f, 0.f};

#pragma unroll
    for (int kt = 0; kt < 256; kt += 32) {
        bf16x8 ah[2], al[2], bh[2], bl[2];
#pragma unroll
        for (int s = 0; s < 2; ++s) {
            ah[s] = *(const bf16x8*)&sAhi[(wm << 5) + (s << 4) + fr][kt + fks];
            al[s] = *(const bf16x8*)&sAlo[(wm << 5) + (s << 4) + fr][kt + fks];
            bh[s] = *(const bf16x8*)&sBhi[(wn << 5) + (s << 4) + fr][kt + fks];
            bl[s] = *(const bf16x8*)&sBlo[(wn << 5) + (s << 4) + fr][kt + fks];
        }
#pragma unroll
        for (int i = 0; i < 2; ++i)
#pragma unroll
            for (int j = 0; j < 2; ++j) {
                acc[i][j] = __builtin_amdgcn_mfma_f32_16x16x32_bf16(ah[i], bh[j], acc[i][j], 0, 0, 0);
                acc[i][j] = __builtin_amdgcn_mfma_f32_16x16x32_bf16(ah[i], bl[j], acc[i][j], 0, 0, 0);
                acc[i][j] = __builtin_amdgcn_mfma_f32_16x16x32_bf16(al[i], bh[j], acc[i][j], 0, 0, 0);
            }
    }

    const int rbase = (lane >> 4) << 2;
    if (!is_nt) {
#pragma unroll
        for (int i = 0; i < 2; ++i)
#pragma unroll
            for (int j = 0; j < 2; ++j) {
                const int gcol = n0 + (wn << 5) + (j << 4) + fr;
                const float bias = b1[gcol];
#pragma unroll
                for (int q = 0; q < 4; ++q) {
                    const int grow = m0 + (wm << 5) + (i << 4) + rbase + q;
                    float x = acc[i][j][q] + bias;
                    x = 1.0f - 2.0f * __builtin_amdgcn_rcpf(
                                          1.0f + __builtin_amdgcn_exp2f(C2F * x));
                    h1[(size_t)grow * 256 + gcol] = x;
                }
            }
    } else {
#pragma unroll
        for (int i = 0; i < 2; ++i)
#pragma unroll
            for (int j = 0; j < 2; ++j) {
                const int gcol = n0 + (wn << 5) + (j << 4) + fr;
#pragma unroll
                for (int q = 0; q < 4; ++q) {
                    const int grow = m0 + (wm << 5) + (i << 4) + rbase + q;
                    Wc[(size_t)grow * 256 + gcol] = acc[i][j][q];
                }
            }
        if ((blk & 3) == 0) {
            const int rr = tid >> 2;
            const int part = (tid & 3) << 6;
            const int grow = m0 + rr;
            const float* Ar = (grow < 256) ? &Wq[(size_t)grow * 256]
                                           : &Wk[(size_t)(grow - 256) * 256];
            float s = 0.f;
#pragma unroll
            for (int e = 0; e < 64; e += 4) {
                f4 a = *(const f4*)&Ar[part + e];
                f4 bv = *(const f4*)&b2[part + e];
                s += a[0] * bv[0] + a[1] * bv[1] + a[2] * bv[2] + a[3] * bv[3];
            }
            sred[rr][tid & 3] = s;
            __syncthreads();
            if (tid < 64) {
                float bias = sred[tid][0] + sred[tid][1] + sred[tid][2] + sred[tid][3];
                const int g2 = m0 + tid;
                bias += (g2 < 256) ? bq[g2] : bk[g2 - 256];
                bc[g2] = bias;
            }
        }
    }
}

// 8-way common-denominator tree: ACCV += sum_{t=0..7} v_t / A_t   (x2^8)
#define TREE8(u0, u1, wv0, wv1, vv0, vv1, ACCV)                              \
    {                                                                        \
        const float A0 = fmaf(u0.x, wv0.x, S8);                              \
        const float A1 = fmaf(u0.y, wv0.y, S8);                              \
        const float A2 = fmaf(u0.z, wv0.z, S8);                              \
        const float A3 = fmaf(u0.w, wv0.w, S8);                              \
        const float A4 = fmaf(u1.x, wv1.x, S8);                              \
        const float A5 = fmaf(u1.y, wv1.y, S8);                              \
        const float A6 = fmaf(u1.z, wv1.z, S8);                              \
        const float A7 = fmaf(u1.w, wv1.w, S8);                              \
        const float m01 = A0 * A1, m23 = A2 * A3;                            \
        const float m45 = A4 * A5, m67 = A6 * A7;                            \
        const float t01 = fmaf(vv0.x, A1, vv0.y * A0);                       \
        const float t23 = fmaf(vv0.z, A3, vv0.w * A2);                       \
        const float t45 = fmaf(vv1.x, A5, vv1.y * A4);                       \
        const float t67 = fmaf(vv1.z, A7, vv1.w * A6);                       \
        const float m03 = m01 * m23, m47 = m45 * m67;                        \
        const float t03 = fmaf(t01, m23, t23 * m01);                         \
        const float t47 = fmaf(t45, m67, t67 * m45);                         \
        const float M = m03 * m47;                                           \
        const float N = fmaf(t03, m47, t47 * m03);                           \
        ACCV = fmaf(N, __builtin_amdgcn_rcpf(M), ACCV);                      \
    }

// ---------------------------------------------------------------------------
// pairwise: per (b, i-tile, j-tile, 64-h chunk) block accumulates into Ep:
//   Ep[b,i,j] += 2^-8 * treesum   (atomicAdd, 4 chunks per element)
// 512 thr, 64x64 tile, 4x2 outputs/thread, 8-way tree.
// (512,6): VGPR cap ~85 -> 24 waves/CU (live set ~60-70; no spill expected).
// ---------------------------------------------------------------------------
__global__ __launch_bounds__(512, 6) void pairwise_kernel(
    const float* __restrict__ uwb, const float* __restrict__ v,
    float* __restrict__ Ep) {
    __shared__ float sU[64][68];
    __shared__ float sW[64][68];
    __shared__ float sV[64];

    const int tid = threadIdx.x;
    const int bb = blockIdx.x;       // 1024 = (4b * 64 tiles) * 4 h-chunks
    const int hcs = bb & 3;
    const int hc = hcs << 6;
    const int tt = bb >> 2;
    const int b = tt >> 6;
    const int i0 = ((tt >> 3) & 7) << 6;
    const int j0 = (tt & 7) << 6;

    const float* ubase = uwb + (size_t)((b << 9) + i0) * 512 + hc;
    const float* wbase = uwb + (size_t)((b << 9) + j0) * 512 + 256 + hc;

    const int sr = tid >> 3;
    const int sc = (tid & 7) << 3;
    {
        f4 a0 = *(const f4*)&ubase[(size_t)sr * 512 + sc];
        f4 a1 = *(const f4*)&ubase[(size_t)sr * 512 + sc + 4];
        f4 b0 = *(const f4*)&wbase[(size_t)sr * 512 + sc];
        f4 b1 = *(const f4*)&wbase[(size_t)sr * 512 + sc + 4];
        *(f4*)&sU[sr][sc] = a0;
        *(f4*)&sU[sr][sc + 4] = a1;
        *(f4*)&sW[sr][sc] = b0;
        *(f4*)&sW[sr][sc + 4] = b1;
    }
    if (tid < 16) *(f4*)&sV[tid << 2] = *(const f4*)&v[hc + (tid << 2)];
    __syncthreads();

    const int ty = tid >> 5;
    const int tx = tid & 31;

    float acc[4][2];
#pragma unroll
    for (int d = 0; d < 4; ++d)
#pragma unroll
        for (int e = 0; e < 2; ++e) acc[d][e] = 0.f;

#pragma unroll 2
    for (int h8 = 0; h8 < 64; h8 += 8) {
        const f4 vv0 = *(const f4*)&sV[h8];
        const f4 vv1 = *(const f4*)&sV[h8 + 4];
        f4 w0[2], w1[2];
#pragma unroll
        for (int e = 0; e < 2; ++e) {
            w0[e] = *(const f4*)&sW[tx + (e << 5)][h8];
            w1[e] = *(const f4*)&sW[tx + (e << 5)][h8 + 4];
        }
#pragma unroll
        for (int d = 0; d < 4; ++d) {
            const f4 u0 = *(const f4*)&sU[ty + (d << 4)][h8];
            const f4 u1 = *(const f4*)&sU[ty + (d << 4)][h8 + 4];
#pragma unroll
            for (int e = 0; e < 2; ++e) TREE8(u0, u1, w0[e], w1[e], vv0, vv1, acc[d][e])
        }
    }

    float* ep = Ep + (size_t)((b << 9) + i0) * 512 + j0;
#pragma unroll
    for (int d = 0; d < 4; ++d)
#pragma unroll
        for (int e = 0; e < 2; ++e)
            atomicAdd(&ep[(size_t)(ty + (d << 4)) * 512 + tx + (e << 5)],
                      acc[d][e] * S8);
}

// out[b,i,j] = Sv - Ep[b,i,j] - Ep[b,j,i]
__global__ __launch_bounds__(256) void sym_kernel(const float* __restrict__ Ep,
                                                  const float* __restrict__ v,
                                                  float* __restrict__ out) {
    __shared__ float t1[64][65];
    __shared__ float t2[64][65];
    __shared__ float red[4];

    const int tid = threadIdx.x;
    const int lane = tid & 63, wv = tid >> 6;

    float x = v[tid];
#pragma unroll
    for (int o = 32; o > 0; o >>= 1) x += __shfl_xor(x, o, 64);
    if (lane == 0) red[wv] = x;

    const int bb = blockIdx.x;
    const int b = bb >> 6;
    const int i0 = ((bb >> 3) & 7) << 6;
    const int j0 = (bb & 7) << 6;

    for (int idx = tid; idx < 4096; idx += 256) {
        const int r = idx >> 6, c = idx & 63;
        t1[r][c] = Ep[(size_t)((b << 9) + i0 + r) * 512 + j0 + c];
        t2[r][c] = Ep[(size_t)((b << 9) + j0 + r) * 512 + i0 + c];
    }
    __syncthreads();
    const float Sv = red[0] + red[1] + red[2] + red[3];
    for (int idx = tid; idx < 4096; idx += 256) {
        const int r = idx >> 6, c = idx & 63;
        out[(size_t)((b << 9) + i0 + r) * 512 + j0 + c] = Sv - (t1[r][c] + t2[c][r]);
    }
}

extern "C" void kernel_launch(void* const* d_in, const int* in_sizes, int n_in,
                              void* d_out, int out_size, void* d_ws, size_t ws_size,
                              hipStream_t stream) {
    const float* X  = (const float*)d_in[0];
    // d_in[1] = Y (unused)
    const float* W1 = (const float*)d_in[2];
    const float* b1 = (const float*)d_in[3];
    const float* W2 = (const float*)d_in[4];
    const float* b2 = (const float*)d_in[5];
    const float* Wq = (const float*)d_in[6];
    const float* bq = (const float*)d_in[7];
    const float* Wk = (const float*)d_in[8];
    const float* bk = (const float*)d_in[9];
    const float* v  = (const float*)d_in[10];
    // d_in[11] = k (unused)

    float* ws  = (float*)d_ws;
    float* h1  = ws;                 // 2048*256 = 524288 f
    float* uwb = ws + 524288;        // 2048*512 = 1048576 f
    float* Wc  = ws + 1572864;       // 512*256  = 131072 f
    float* bc  = ws + 1703936;       // 512 f
    float* Ep  = ws + 1704448;       // 1048576 f (single slice, atomic acc)
    float* out = (float*)d_out;

    // fused: h1 = tanh(X@W1^T+b1); Wc/bc fold; blocks [160,224) zero Ep
    gemm_stage1<<<224, 256, 0, stream>>>(X, W1, b1, Wq, Wk, W2, b2, bq, bk,
                                         h1, Wc, bc, Ep);
    // uwb[:, :256] = min(exp2(C2*Q - 8), 4), uwb[:, 256:] = min(exp2(C2*K), 1024)
    gemm_fullk<2><<<dim3(32, 8), 256, 0, stream>>>(h1, Wc, Wc + 65536, bc,
                                                   bc + 256, uwb, 512);
    // Ep[b,i,j] += 2^-8 * treesum   (atomicAdd, 4 h-chunks per element)
    pairwise_kernel<<<1024, 512, 0, stream>>>(uwb, v, Ep);
    // out = Sv - Ep - Ep^T
    sym_kernel<<<256, 256, 0, stream>>>(Ep, v, out);
}

// Round 15
// 57.006 us; speedup vs baseline: 1.2124x; 1.2124x over previous
//
#include <hip/hip_runtime.h>

// Problem: B=4, N=512, D=256, H=256, M = B*N = 2048
// out[b,i,j] = 0.5*(E + E^T),  E[b,i,j] = sum_h v[h]*tanh(Q[b,i,h]+K[b,j,h])
// tanh(q+k) = 1 - 2/(1+e^{2q}e^{2k}); u=exp2(C2*q), w=exp2(C2*k), C2=2*log2(e)
// P_ij = sum_h v_h/(1+u_ih w_jh);  out_ij = Sv - P_ij - P_ji
// 8-way rcp batching (1 rcp per 8 terms) via common-denominator tree.
// Overflow: u pre-scaled by 2^-8 in gemm epilogue (u' = exp2(C2*Q-8), clamp 4;
//   w = exp2(C2*K), clamp 1024).  Leaf A' = fma(u',w,2^-8) = 2^-8*(1+uw).
//   M' = prod8 <= 4096^8 ~ 8e28 (safe); fold 2^-8 into the final atomic.
// GEMM fold: Q = h1 @ (Wq@W2)^T + (Wq@b2+bq)
// Round 15: exact round-10 restore (best measured: 57.4us).
//   Rejected with evidence: (512,8)/(512,6) VGPR pins -> scratch spills
//   (r5: 180MB, r14: 91MB); direct-output atomics (r11: 17M RMW, 324us);
//   4-slice no-atomic Ep (r12: +1.7us); 64x32 GEMM re-tile (r13: +2.1us);
//   ext-vector packed-f32 (r8: compiler scalarizes, flat);
//   hipMemsetAsync Ep (r9: ~40us fill dispatch -> fused zeroing here).

typedef float f4 __attribute__((ext_vector_type(4)));
typedef float f32x4 __attribute__((ext_vector_type(4)));
typedef __bf16 bf16x8 __attribute__((ext_vector_type(8)));

#define C2F 2.8853900817779268f
#define S8  0.00390625f   // 2^-8

__device__ inline unsigned short f2bf(float f) {
    unsigned u = __float_as_uint(f);
    unsigned r = (u + 0x7fffu + ((u >> 16) & 1u)) >> 16;
    return (unsigned short)r;
}
__device__ inline float bf2f(unsigned short h) {
    return __uint_as_float(((unsigned)h) << 16);
}

__device__ inline void split4(const f4 a, unsigned short* hp, unsigned short* lp) {
    unsigned short h[4], l[4];
#pragma unroll
    for (int t = 0; t < 4; ++t) {
        h[t] = f2bf(a[t]);
        l[t] = f2bf(a[t] - bf2f(h[t]));
    }
    uint2 hv, lv;
    hv.x = (unsigned)h[0] | ((unsigned)h[1] << 16);
    hv.y = (unsigned)h[2] | ((unsigned)h[3] << 16);
    lv.x = (unsigned)l[0] | ((unsigned)l[1] << 16);
    lv.y = (unsigned)l[2] | ((unsigned)l[3] << 16);
    *(uint2*)hp = hv;
    *(uint2*)lp = lv;
}

// ---------------------------------------------------------------------------
// gemm_fullk: C[m,n] = act(sum_k A[m,k]*Wsel[n,k] + bias[n]), K=256 resident.
// ACT==2: col<256 -> min(exp2(C2*x-8),4); col>=256 -> min(exp2(C2*x),1024)
// ---------------------------------------------------------------------------
template <int ACT>
__global__ __launch_bounds__(256) void gemm_fullk(
    const float* __restrict__ A, const float* __restrict__ Wa,
    const float* __restrict__ Wb, const float* __restrict__ ba,
    const float* __restrict__ bb2, float* __restrict__ C, int Nn) {
    __shared__ unsigned short sAhi[64][264];
    __shared__ unsigned short sAlo[64][264];
    __shared__ unsigned short sBhi[64][264];
    __shared__ unsigned short sBlo[64][264];

    const int tid = threadIdx.x;
    const int m0 = blockIdx.x << 6;
    const int n0 = blockIdx.y << 6;

    const float* Atile = A + (size_t)m0 * 256;
    const float* Wtile = (n0 < 256) ? (Wa + (size_t)n0 * 256)
                                    : (Wb + (size_t)(n0 - 256) * 256);
    const int col4 = (tid & 63) << 2;
    const int rgrp = tid >> 6;
#pragma unroll
    for (int t = 0; t < 16; ++t) {
        const int row = (t << 2) + rgrp;
        f4 av = *(const f4*)&Atile[(size_t)row * 256 + col4];
        f4 wv = *(const f4*)&Wtile[(size_t)row * 256 + col4];
        split4(av, &sAhi[row][col4], &sAlo[row][col4]);
        split4(wv, &sBhi[row][col4], &sBlo[row][col4]);
    }
    __syncthreads();

    const int lane = tid & 63;
    const int wav = tid >> 6;
    const int wm = wav >> 1, wn = wav & 1;
    const int fr = lane & 15;
    const int fks = (lane >> 4) << 3;

    f32x4 acc[2][2];
#pragma unroll
    for (int i = 0; i < 2; ++i)
#pragma unroll
        for (int j = 0; j < 2; ++j) acc[i][j] = (f32x4){0.f, 0.f, 0.f, 0.f};

#pragma unroll
    for (int kt = 0; kt < 256; kt += 32) {
        bf16x8 ah[2], al[2], bh[2], bl[2];
#pragma unroll
        for (int s = 0; s < 2; ++s) {
            ah[s] = *(const bf16x8*)&sAhi[(wm << 5) + (s << 4) + fr][kt + fks];
            al[s] = *(const bf16x8*)&sAlo[(wm << 5) + (s << 4) + fr][kt + fks];
            bh[s] = *(const bf16x8*)&sBhi[(wn << 5) + (s << 4) + fr][kt + fks];
            bl[s] = *(const bf16x8*)&sBlo[(wn << 5) + (s << 4) + fr][kt + fks];
        }
#pragma unroll
        for (int i = 0; i < 2; ++i)
#pragma unroll
            for (int j = 0; j < 2; ++j) {
                acc[i][j] = __builtin_amdgcn_mfma_f32_16x16x32_bf16(ah[i], bh[j], acc[i][j], 0, 0, 0);
                acc[i][j] = __builtin_amdgcn_mfma_f32_16x16x32_bf16(ah[i], bl[j], acc[i][j], 0, 0, 0);
                acc[i][j] = __builtin_amdgcn_mfma_f32_16x16x32_bf16(al[i], bh[j], acc[i][j], 0, 0, 0);
            }
    }

    const int rbase = (lane >> 4) << 2;
#pragma unroll
    for (int i = 0; i < 2; ++i) {
#pragma unroll
        for (int j = 0; j < 2; ++j) {
            const int gcol = n0 + (wn << 5) + (j << 4) + fr;
            const float bias = (ACT == 2 && gcol >= 256) ? bb2[gcol - 256] : ba[gcol];
#pragma unroll
            for (int q = 0; q < 4; ++q) {
                const int grow = m0 + (wm << 5) + (i << 4) + rbase + q;
                float x = acc[i][j][q] + bias;
                if (ACT == 1)
                    x = 1.0f - 2.0f * __builtin_amdgcn_rcpf(
                                          1.0f + __builtin_amdgcn_exp2f(C2F * x));
                if (ACT == 2) {
                    if (gcol < 256)
                        x = fminf(__builtin_amdgcn_exp2f(C2F * x - 8.0f), 4.0f);
                    else
                        x = fminf(__builtin_amdgcn_exp2f(C2F * x), 1024.0f);
                }
                C[(size_t)grow * Nn + gcol] = x;
            }
        }
    }
}

// ---------------------------------------------------------------------------
// gemm_stage1: fused launch.
//  blocks [0,128): h1 = tanh(X @ W1^T + b1)
//  blocks [128,160): Wc = [Wq;Wk] @ W2 (B not transp.), bc = Asel@b2 + bias
//  blocks [160,224): zero Ep (1M floats; replaces 40us hipMemsetAsync fill)
// ---------------------------------------------------------------------------
__global__ __launch_bounds__(256) void gemm_stage1(
    const float* __restrict__ X, const float* __restrict__ W1,
    const float* __restrict__ b1, const float* __restrict__ Wq,
    const float* __restrict__ Wk, const float* __restrict__ W2,
    const float* __restrict__ b2, const float* __restrict__ bq,
    const float* __restrict__ bk, float* __restrict__ h1,
    float* __restrict__ Wc, float* __restrict__ bc,
    float* __restrict__ Ep) {
    __shared__ unsigned short sAhi[64][264];
    __shared__ unsigned short sAlo[64][264];
    __shared__ unsigned short sBhi[64][264];
    __shared__ unsigned short sBlo[64][264];
    __shared__ float sred[64][4];

    const int tid = threadIdx.x;

    if (blockIdx.x >= 160) {
        // Ep zeroing: 64 blocks x 256 thr x 16 f4 = 1048576 floats
        const int zb = blockIdx.x - 160;
        f4* dst = (f4*)(Ep + (size_t)zb * 16384) + tid;
        const f4 z = (f4){0.f, 0.f, 0.f, 0.f};
#pragma unroll
        for (int t = 0; t < 16; ++t) dst[t * 256] = z;
        return;
    }

    const bool is_nt = (blockIdx.x >= 128);
    const int blk = is_nt ? (blockIdx.x - 128) : blockIdx.x;
    const int m0 = (blk >> 2) << 6;
    const int n0 = (blk & 3) << 6;

    const int col4 = (tid & 63) << 2;
    const int rgrp = tid >> 6;

    if (!is_nt) {
        const float* Atile = X + (size_t)m0 * 256;
        const float* Wtile = W1 + (size_t)n0 * 256;
#pragma unroll
        for (int t = 0; t < 16; ++t) {
            const int row = (t << 2) + rgrp;
            f4 av = *(const f4*)&Atile[(size_t)row * 256 + col4];
            f4 wv = *(const f4*)&Wtile[(size_t)row * 256 + col4];
            split4(av, &sAhi[row][col4], &sAlo[row][col4]);
            split4(wv, &sBhi[row][col4], &sBlo[row][col4]);
        }
    } else {
        const float* Atile = (m0 < 256) ? (Wq + (size_t)m0 * 256)
                                        : (Wk + (size_t)(m0 - 256) * 256);
#pragma unroll
        for (int t = 0; t < 16; ++t) {
            const int row = (t << 2) + rgrp;
            f4 av = *(const f4*)&Atile[(size_t)row * 256 + col4];
            split4(av, &sAhi[row][col4], &sAlo[row][col4]);
        }
        const int c4 = (tid & 15) << 2;
        const int kg = tid >> 4;
#pragma unroll
        for (int t = 0; t < 16; ++t) {
            const int k = (t << 4) + kg;
            f4 wv = *(const f4*)&W2[(size_t)k * 256 + n0 + c4];
#pragma unroll
            for (int q = 0; q < 4; ++q) {
                unsigned short hi = f2bf(wv[q]);
                sBhi[c4 + q][k] = hi;
                sBlo[c4 + q][k] = f2bf(wv[q] - bf2f(hi));
            }
        }
    }
    __syncthreads();

    const int lane = tid & 63;
    const int wav = tid >> 6;
    const int wm = wav >> 1, wn = wav & 1;
    const int fr = lane & 15;
    const int fks = (lane >> 4) << 3;

    f32x4 acc[2][2];
#pragma unroll
    for (int i = 0; i < 2; ++i)
#pragma unroll
        for (int j = 0; j < 2; ++j) acc[i][j] = (f32x4){0.f, 0.f, 0.f, 0.f};

#pragma unroll
    for (int kt = 0; kt < 256; kt += 32) {
        bf16x8 ah[2], al[2], bh[2], bl[2];
#pragma unroll
        for (int s = 0; s < 2; ++s) {
            ah[s] = *(const bf16x8*)&sAhi[(wm << 5) + (s << 4) + fr][kt + fks];
            al[s] = *(const bf16x8*)&sAlo[(wm << 5) + (s << 4) + fr][kt + fks];
            bh[s] = *(const bf16x8*)&sBhi[(wn << 5) + (s << 4) + fr][kt + fks];
            bl[s] = *(const bf16x8*)&sBlo[(wn << 5) + (s << 4) + fr][kt + fks];
        }
#pragma unroll
        for (int i = 0; i < 2; ++i)
#pragma unroll
            for (int j = 0; j < 2; ++j) {
                acc[i][j] = __builtin_amdgcn_mfma_f32_16x16x32_bf16(ah[i], bh[j], acc[i][j], 0, 0, 0);
                acc[i][j] = __builtin_amdgcn_mfma_f32_16x16x32_bf16(ah[i], bl[j], acc[i][j], 0, 0, 0);
                acc[i][j] = __builtin_amdgcn_mfma_f32_16x16x32_bf16(al[i], bh[j], acc[i][j], 0, 0, 0);
            }
    }

    const int rbase = (lane >> 4) << 2;
    if (!is_nt) {
#pragma unroll
        for (int i = 0; i < 2; ++i)
#pragma unroll
            for (int j = 0; j < 2; ++j) {
                const int gcol = n0 + (wn << 5) + (j << 4) + fr;
                const float bias = b1[gcol];
#pragma unroll
                for (int q = 0; q < 4; ++q) {
                    const int grow = m0 + (wm << 5) + (i << 4) + rbase + q;
                    float x = acc[i][j][q] + bias;
                    x = 1.0f - 2.0f * __builtin_amdgcn_rcpf(
                                          1.0f + __builtin_amdgcn_exp2f(C2F * x));
                    h1[(size_t)grow * 256 + gcol] = x;
                }
            }
    } else {
#pragma unroll
        for (int i = 0; i < 2; ++i)
#pragma unroll
            for (int j = 0; j < 2; ++j) {
                const int gcol = n0 + (wn << 5) + (j << 4) + fr;
#pragma unroll
                for (int q = 0; q < 4; ++q) {
                    const int grow = m0 + (wm << 5) + (i << 4) + rbase + q;
                    Wc[(size_t)grow * 256 + gcol] = acc[i][j][q];
                }
            }
        if ((blk & 3) == 0) {
            const int rr = tid >> 2;
            const int part = (tid & 3) << 6;
            const int grow = m0 + rr;
            const float* Ar = (grow < 256) ? &Wq[(size_t)grow * 256]
                                           : &Wk[(size_t)(grow - 256) * 256];
            float s = 0.f;
#pragma unroll
            for (int e = 0; e < 64; e += 4) {
                f4 a = *(const f4*)&Ar[part + e];
                f4 bv = *(const f4*)&b2[part + e];
                s += a[0] * bv[0] + a[1] * bv[1] + a[2] * bv[2] + a[3] * bv[3];
            }
            sred[rr][tid & 3] = s;
            __syncthreads();
            if (tid < 64) {
                float bias = sred[tid][0] + sred[tid][1] + sred[tid][2] + sred[tid][3];
                const int g2 = m0 + tid;
                bias += (g2 < 256) ? bq[g2] : bk[g2 - 256];
                bc[g2] = bias;
            }
        }
    }
}

// 8-way common-denominator tree: ACCV += sum_{t=0..7} v_t / A_t   (x2^8)
#define TREE8(u0, u1, wv0, wv1, vv0, vv1, ACCV)                              \
    {                                                                        \
        const float A0 = fmaf(u0.x, wv0.x, S8);                              \
        const float A1 = fmaf(u0.y, wv0.y, S8);                              \
        const float A2 = fmaf(u0.z, wv0.z, S8);                              \
        const float A3 = fmaf(u0.w, wv0.w, S8);                              \
        const float A4 = fmaf(u1.x, wv1.x, S8);                              \
        const float A5 = fmaf(u1.y, wv1.y, S8);                              \
        const float A6 = fmaf(u1.z, wv1.z, S8);                              \
        const float A7 = fmaf(u1.w, wv1.w, S8);                              \
        const float m01 = A0 * A1, m23 = A2 * A3;                            \
        const float m45 = A4 * A5, m67 = A6 * A7;                            \
        const float t01 = fmaf(vv0.x, A1, vv0.y * A0);                       \
        const float t23 = fmaf(vv0.z, A3, vv0.w * A2);                       \
        const float t45 = fmaf(vv1.x, A5, vv1.y * A4);                       \
        const float t67 = fmaf(vv1.z, A7, vv1.w * A6);                       \
        const float m03 = m01 * m23, m47 = m45 * m67;                        \
        const float t03 = fmaf(t01, m23, t23 * m01);                         \
        const float t47 = fmaf(t45, m67, t67 * m45);                         \
        const float M = m03 * m47;                                           \
        const float N = fmaf(t03, m47, t47 * m03);                           \
        ACCV = fmaf(N, __builtin_amdgcn_rcpf(M), ACCV);                      \
    }

// ---------------------------------------------------------------------------
// pairwise: per (b, i-tile, j-tile, 64-h chunk) block accumulates into Ep:
//   Ep[b,i,j] += 2^-8 * treesum   (atomicAdd, 4 chunks per element)
// 512 thr, 64x64 tile, 4x2 outputs/thread, 8-way tree. (512,4) -> VGPR 64,
// no spill (measured r10: best total 57.4us).
// ---------------------------------------------------------------------------
__global__ __launch_bounds__(512, 4) void pairwise_kernel(
    const float* __restrict__ uwb, const float* __restrict__ v,
    float* __restrict__ Ep) {
    __shared__ float sU[64][68];
    __shared__ float sW[64][68];
    __shared__ float sV[64];

    const int tid = threadIdx.x;
    const int bb = blockIdx.x;       // 1024 = (4b * 64 tiles) * 4 h-chunks
    const int hcs = bb & 3;
    const int hc = hcs << 6;
    const int tt = bb >> 2;
    const int b = tt >> 6;
    const int i0 = ((tt >> 3) & 7) << 6;
    const int j0 = (tt & 7) << 6;

    const float* ubase = uwb + (size_t)((b << 9) + i0) * 512 + hc;
    const float* wbase = uwb + (size_t)((b << 9) + j0) * 512 + 256 + hc;

    const int sr = tid >> 3;         // 0..63
    const int sc = (tid & 7) << 3;   // 0,8,..,56
    {
        f4 a0 = *(const f4*)&ubase[(size_t)sr * 512 + sc];
        f4 a1 = *(const f4*)&ubase[(size_t)sr * 512 + sc + 4];
        f4 b0 = *(const f4*)&wbase[(size_t)sr * 512 + sc];
        f4 b1 = *(const f4*)&wbase[(size_t)sr * 512 + sc + 4];
        *(f4*)&sU[sr][sc] = a0;
        *(f4*)&sU[sr][sc + 4] = a1;
        *(f4*)&sW[sr][sc] = b0;
        *(f4*)&sW[sr][sc + 4] = b1;
    }
    if (tid < 16) *(f4*)&sV[tid << 2] = *(const f4*)&v[hc + (tid << 2)];
    __syncthreads();

    const int ty = tid >> 5;   // 0..15: rows ty+16d
    const int tx = tid & 31;   // 0..31: cols tx+32e

    float acc[4][2];
#pragma unroll
    for (int d = 0; d < 4; ++d)
#pragma unroll
        for (int e = 0; e < 2; ++e) acc[d][e] = 0.f;

#pragma unroll 2
    for (int h8 = 0; h8 < 64; h8 += 8) {
        const f4 vv0 = *(const f4*)&sV[h8];
        const f4 vv1 = *(const f4*)&sV[h8 + 4];
        f4 w0[2], w1[2];
#pragma unroll
        for (int e = 0; e < 2; ++e) {
            w0[e] = *(const f4*)&sW[tx + (e << 5)][h8];
            w1[e] = *(const f4*)&sW[tx + (e << 5)][h8 + 4];
        }
#pragma unroll
        for (int d = 0; d < 4; ++d) {
            const f4 u0 = *(const f4*)&sU[ty + (d << 4)][h8];
            const f4 u1 = *(const f4*)&sU[ty + (d << 4)][h8 + 4];
#pragma unroll
            for (int e = 0; e < 2; ++e) TREE8(u0, u1, w0[e], w1[e], vv0, vv1, acc[d][e])
        }
    }

    float* ep = Ep + (size_t)((b << 9) + i0) * 512 + j0;
#pragma unroll
    for (int d = 0; d < 4; ++d)
#pragma unroll
        for (int e = 0; e < 2; ++e)
            atomicAdd(&ep[(size_t)(ty + (d << 4)) * 512 + tx + (e << 5)],
                      acc[d][e] * S8);
}

// out[b,i,j] = Sv - Ep[b,i,j] - Ep[b,j,i]
__global__ __launch_bounds__(256) void sym_kernel(const float* __restrict__ Ep,
                                                  const float* __restrict__ v,
                                                  float* __restrict__ out) {
    __shared__ float t1[64][65];
    __shared__ float t2[64][65];
    __shared__ float red[4];

    const int tid = threadIdx.x;
    const int lane = tid & 63, wv = tid >> 6;

    float x = v[tid];
#pragma unroll
    for (int o = 32; o > 0; o >>= 1) x += __shfl_xor(x, o, 64);
    if (lane == 0) red[wv] = x;

    const int bb = blockIdx.x;
    const int b = bb >> 6;
    const int i0 = ((bb >> 3) & 7) << 6;
    const int j0 = (bb & 7) << 6;

    for (int idx = tid; idx < 4096; idx += 256) {
        const int r = idx >> 6, c = idx & 63;
        t1[r][c] = Ep[(size_t)((b << 9) + i0 + r) * 512 + j0 + c];
        t2[r][c] = Ep[(size_t)((b << 9) + j0 + r) * 512 + i0 + c];
    }
    __syncthreads();
    const float Sv = red[0] + red[1] + red[2] + red[3];
    for (int idx = tid; idx < 4096; idx += 256) {
        const int r = idx >> 6, c = idx & 63;
        out[(size_t)((b << 9) + i0 + r) * 512 + j0 + c] = Sv - (t1[r][c] + t2[c][r]);
    }
}

extern "C" void kernel_launch(void* const* d_in, const int* in_sizes, int n_in,
                              void* d_out, int out_size, void* d_ws, size_t ws_size,
                              hipStream_t stream) {
    const float* X  = (const float*)d_in[0];
    // d_in[1] = Y (unused)
    const float* W1 = (const float*)d_in[2];
    const float* b1 = (const float*)d_in[3];
    const float* W2 = (const float*)d_in[4];
    const float* b2 = (const float*)d_in[5];
    const float* Wq = (const float*)d_in[6];
    const float* bq = (const float*)d_in[7];
    const float* Wk = (const float*)d_in[8];
    const float* bk = (const float*)d_in[9];
    const float* v  = (const float*)d_in[10];
    // d_in[11] = k (unused)

    float* ws  = (float*)d_ws;
    float* h1  = ws;                 // 2048*256 = 524288 f
    float* uwb = ws + 524288;        // 2048*512 = 1048576 f
    float* Wc  = ws + 1572864;       // 512*256  = 131072 f
    float* bc  = ws + 1703936;       // 512 f
    float* Ep  = ws + 1704448;       // 1048576 f (single slice, atomic acc)
    float* out = (float*)d_out;

    // fused: h1 = tanh(X@W1^T+b1); Wc/bc fold; blocks [160,224) zero Ep
    gemm_stage1<<<224, 256, 0, stream>>>(X, W1, b1, Wq, Wk, W2, b2, bq, bk,
                                         h1, Wc, bc, Ep);
    // uwb[:, :256] = min(exp2(C2*Q - 8), 4), uwb[:, 256:] = min(exp2(C2*K), 1024)
    gemm_fullk<2><<<dim3(32, 8), 256, 0, stream>>>(h1, Wc, Wc + 65536, bc,
                                                   bc + 256, uwb, 512);
    // Ep[b,i,j] += 2^-8 * treesum   (atomicAdd, 4 h-chunks per element)
    pairwise_kernel<<<1024, 512, 0, stream>>>(uwb, v, Ep);
    // out = Sv - Ep - Ep^T
    sym_kernel<<<256, 256, 0, stream>>>(Ep, v, out);
}